// Round 1
// baseline (292.748 us; speedup 1.0000x reference)
//
#include <hip/hip_runtime.h>
#include <stdint.h>

// ---------------------------------------------------------------------------
// DS_MultiHeadLatentAttention, round 9.
// attn7: K/V are L2-resident per XCD (4 combos x 512 KB = 2 MB), so LDS
// staging + its 2 barriers/chunk + vmcnt(0) drains were pure overhead.
// New attn: direct-global K/V fragment loads (L1/L2 hits), swapped QK^T
// (S^T = mfma(K,Q)) so P-values are k-adjacent per lane -> packed b64 Ps
// writes + per-lane scalar row-sum, one q-tile (64 rows) per block,
// grid 1024 (8192 waves, 2x), LDS 50KB -> 20KB, launch_bounds(512,6) for
// 3 blocks/CU. Longest tiles dispatched first. prep/gemms unchanged.
// Dispatches: prep, gemmQLat(640), gemmKV(1024), attn(1024), gemmO(512).
// Workspace (34 MB, time-phased):
//   [0,8M)   Qp      [8,16M)  Kb -> Kp      [16,24M) Qb -> VpT
//   [24,32M) WqT(2M)|Lat(2M)|WdT(.5M)|WkvT(1M) -> Attn
//   [32,34M) WoT
// ---------------------------------------------------------------------------

#define DM 1024
#define NH 16
#define DK 64
#define LL 2048

typedef float  f32x4  __attribute__((ext_vector_type(4)));
typedef __bf16 bf16x8 __attribute__((ext_vector_type(8)));
typedef short  s16x8  __attribute__((ext_vector_type(8)));

__device__ __forceinline__ unsigned short f2bf(float f) {
    union { float f; unsigned int u; } v; v.f = f;
    return (unsigned short)((v.u + 0x7fffu + ((v.u >> 16) & 1u)) >> 16);
}
__device__ __forceinline__ unsigned int pack2(float a, float b) {
    return (unsigned int)f2bf(a) | ((unsigned int)f2bf(b) << 16);
}
// truncating pack (matches old Ps path's >>16 truncation; exp values only)
__device__ __forceinline__ unsigned int packt(float a, float b) {
    union { float f; unsigned int u; } x, y; x.f = a; y.f = b;
    return (x.u >> 16) | (y.u & 0xffff0000u);
}
__device__ __forceinline__ bf16x8 ld8(const unsigned short* p) {
    s16x8 s = *(const s16x8*)p;
    return __builtin_bit_cast(bf16x8, s);
}
__device__ __forceinline__ void gl16(const void* g, void* l) {
    __builtin_amdgcn_global_load_lds((__attribute__((address_space(1))) void*)(g),
                                     (__attribute__((address_space(3))) void*)(l),
                                     16, 0, 0);
}

// ---------------------------------------------------------------------------
// prep: 5 weight transposes (fp32 [K][N] -> bf16 [N][K]) + queries/keys
// fp32 -> bf16. Grid = 4864.
// ---------------------------------------------------------------------------
__global__ __launch_bounds__(256)
void prep_k(const float* __restrict__ Wq, const float* __restrict__ Wd,
            const float* __restrict__ Wk, const float* __restrict__ Wv,
            const float* __restrict__ Wo, const float* __restrict__ queries,
            const float* __restrict__ keys,
            unsigned short* __restrict__ WqT, unsigned short* __restrict__ WdT,
            unsigned short* __restrict__ WkvT, unsigned short* __restrict__ WoT,
            unsigned short* __restrict__ Qb, unsigned short* __restrict__ Kb) {
    int bid = blockIdx.x;
    const int t = threadIdx.x;

    const float* W; unsigned short* WT; int TK, TN;
    if (bid < 1024)      { W = Wq; WT = WqT;  TK = 1024; TN = 1024; }
    else if (bid < 1280) { bid -= 1024; W = Wd; WT = WdT; TK = 1024; TN = 256; }
    else if (bid < 1536) { bid -= 1280; W = Wk; WT = WkvT; TK = 256; TN = 1024; }
    else if (bid < 1792) { bid -= 1536; W = Wv; WT = WkvT + (size_t)1024 * 256; TK = 256; TN = 1024; }
    else if (bid < 2816) { bid -= 1792; W = Wo; WT = WoT;  TK = 1024; TN = 1024; }
    else {
        bid -= 2816;
        const float* src; unsigned short* dst;
        if (bid < 1024) { src = queries; dst = Qb; }
        else            { bid -= 1024; src = keys; dst = Kb; }
        const size_t base = (size_t)bid * 4096;
#pragma unroll
        for (int i = 0; i < 4; ++i) {
            float4 f = *(const float4*)(src + base + (size_t)(i * 256 + t) * 4);
            uint2 u = { pack2(f.x, f.y), pack2(f.z, f.w) };
            *(uint2*)(dst + base + (size_t)(i * 256 + t) * 4) = u;
        }
        return;
    }
    __shared__ float tile[32][33];
    const int tx = t & 31, ty = t >> 5;
    const int bx = bid % (TK / 32), by = bid / (TK / 32);
    const int k0 = bx * 32, n0 = by * 32;
#pragma unroll
    for (int i = 0; i < 4; ++i)
        tile[ty + 8 * i][tx] = W[(size_t)(k0 + ty + 8 * i) * TN + n0 + tx];
    __syncthreads();
#pragma unroll
    for (int i = 0; i < 4; ++i)
        WT[(size_t)(n0 + ty + 8 * i) * TK + k0 + tx] = f2bf(tile[tx][ty + 8 * i]);
}

// ---------------------------------------------------------------------------
// GEMM staging + compute helpers (128x64 tile, BK=64).
// ---------------------------------------------------------------------------
__device__ __forceinline__ void stage6(const unsigned short* gA, const unsigned short* gB,
                                       int kk, int K,
                                       unsigned short* lA, unsigned short* lB) {
#pragma unroll
    for (int s = 0; s < 4; ++s) gl16(gA + kk + (size_t)s * 8 * K, lA + s * 512);
#pragma unroll
    for (int s = 0; s < 2; ++s) gl16(gB + kk + (size_t)s * 8 * K, lB + s * 512);
}

__device__ __forceinline__ void mfma16(const unsigned short* As, const unsigned short* Bs,
                                       const int aoff[4][2], const int boff[2][2],
                                       f32x4 acc[4][2]) {
#pragma unroll
    for (int ks = 0; ks < 2; ++ks) {
        bf16x8 a[4], b[2];
#pragma unroll
        for (int i = 0; i < 4; ++i) a[i] = ld8(As + aoff[i][ks]);
#pragma unroll
        for (int j = 0; j < 2; ++j) b[j] = ld8(Bs + boff[j][ks]);
#pragma unroll
        for (int i = 0; i < 4; ++i)
#pragma unroll
            for (int j = 0; j < 2; ++j)
                acc[i][j] = __builtin_amdgcn_mfma_f32_16x16x32_bf16(a[i], b[j], acc[i][j], 0, 0, 0);
    }
}

// ---------------------------------------------------------------------------
// GEMM 128(M) x 64(N) tile, BK=64, 4 waves 2x2 (wave = 64m x 32n, 4x2 accs).
// LDS double-buffer (Sh0/Sh1, compile-time selection), one barrier per iter.
// XCD-clustered: xcd = bid&7 sweeps all n over a small m-window.
// MODE 0: fused Q+Lat (K=1024). bid<512: Qb@WqT+bq -> Qp bf16 [row*1024].
//         bid>=512 (128 blocks): Kb@WdT+bd -> Lat bf16 [row*256].
// MODE 1: Attn@WoT+bo -> f32 [row*1024]. grid 512, K=1024.
// MODE 2: fused K|V (K=256, N=2048): col<1024 -> Kp bf16 [row*1024];
//         col>=1024 -> VpT [b][col-1024][l] via LDS-transposed epilogue.
// ---------------------------------------------------------------------------
template<int MODE>
__global__ __launch_bounds__(256)
void gemm_k(const unsigned short* __restrict__ Ap, const unsigned short* __restrict__ Bt,
            const float* __restrict__ bias, void* __restrict__ Cp,
            const unsigned short* __restrict__ Ap2, const unsigned short* __restrict__ Bt2,
            const float* __restrict__ bias2, void* __restrict__ Cp2,
            int K) {
    __shared__ unsigned short Sh0[12288];     // As0 8192 + Bs0 4096 shorts (24 KB)
    __shared__ unsigned short Sh1[12288];     // As1 + Bs1 (24 KB)

    int bid = blockIdx.x;
    const unsigned short* A;
    const unsigned short* B;
    const float* bs;
    bool second = false;
    int m0, n0;
    if (MODE == 0 && bid >= 512) {            // Lat part: 128 blocks, N=256
        bid -= 512; A = Ap2; B = Bt2; bs = bias2; second = true;
        const int xcd = bid & 7, s = bid >> 3;            // s in [0,16)
        n0 = (s & 3) * 64; m0 = (xcd * 4 + (s >> 2)) * 128;
    } else {
        A = Ap; B = Bt; bs = bias;
        const int xcd = bid & 7, s = bid >> 3;
        if (MODE == 2) { n0 = (s & 31) * 64; m0 = (xcd * 4 + (s >> 5)) * 128; }
        else           { n0 = (s & 15) * 64; m0 = (xcd * 4 + (s >> 4)) * 128; }
    }

    const int t = threadIdx.x, lane = t & 63, wv = t >> 6;
    const int quad = lane >> 4, l15 = lane & 15;

    const int lr8 = lane >> 3;                 // 0..7
    const int g8 = (lane & 7) ^ (lr8 & 7);     // swizzled k-chunk
    const unsigned short* gA = A + (size_t)(m0 + wv * 32 + lr8) * K + g8 * 8;
    const unsigned short* gB = B + (size_t)(n0 + wv * 16 + lr8) * K + g8 * 8;
    unsigned short* lA0 = Sh0 + wv * 2048;
    unsigned short* lB0 = Sh0 + 8192 + wv * 1024;
    unsigned short* lA1 = Sh1 + wv * 2048;
    unsigned short* lB1 = Sh1 + 8192 + wv * 1024;

    int aoff[4][2], boff[2][2];
#pragma unroll
    for (int i = 0; i < 4; ++i) {
        const int ra = (wv >> 1) * 64 + i * 16 + l15;
#pragma unroll
        for (int ks = 0; ks < 2; ++ks)
            aoff[i][ks] = ra * 64 + (((ks * 4 + quad) ^ (ra & 7)) << 3);
    }
#pragma unroll
    for (int j = 0; j < 2; ++j) {
        const int rb = (wv & 1) * 32 + j * 16 + l15;
#pragma unroll
        for (int ks = 0; ks < 2; ++ks)
            boff[j][ks] = rb * 64 + (((ks * 4 + quad) ^ (rb & 7)) << 3);
    }

    f32x4 acc[4][2] = {};
    const int niter = K >> 6;                  // 16 or 4 (always even)

    stage6(gA, gB, 0, K, lA0, lB0);
    __syncthreads();                           // tile 0 resident in Sh0
    for (int it = 0; it < niter; it += 2) {
        const int kk = it << 6;
        // even iter: prefetch -> Sh1, compute Sh0
        if (it + 1 < niter) stage6(gA, gB, kk + 64, K, lA1, lB1);
        mfma16(Sh0, Sh0 + 8192, aoff, boff, acc);
        __syncthreads();                       // drains Sh1 gl16s (overlapped)
        if (it + 1 < niter) {
            // odd iter: prefetch -> Sh0, compute Sh1
            if (it + 2 < niter) stage6(gA, gB, kk + 128, K, lA0, lB0);
            mfma16(Sh1, Sh1 + 8192, aoff, boff, acc);
            __syncthreads();
        }
    }

    const bool isV = (MODE == 2) && (n0 >= 1024);
    if (!isV) {
#pragma unroll
        for (int j = 0; j < 2; ++j) {
            const int col = n0 + (wv & 1) * 32 + j * 16 + l15;
            const float bvv = bs[col];
#pragma unroll
            for (int i = 0; i < 4; ++i) {
                const int rowb = m0 + (wv >> 1) * 64 + i * 16 + quad * 4;
#pragma unroll
                for (int r = 0; r < 4; ++r) {
                    const float v = acc[i][j][r] + bvv;
                    const int row = rowb + r;
                    if (MODE == 1)
                        ((float*)Cp)[(size_t)row * 1024 + col] = v;
                    else if (second)
                        ((unsigned short*)Cp2)[(size_t)row * 256 + col] = f2bf(v);
                    else
                        ((unsigned short*)Cp)[(size_t)row * 1024 + col] = f2bf(v);
                }
            }
        }
    } else {
        // V part: transpose 128tok x 64d tile through LDS, store coalesced
        // to VpT[(b*1024 + d)*2048 + l].  Ld layout: [d][tok], stride 136.
        unsigned short* Ld = Sh0;               // 64*136 shorts = 17408 B
#pragma unroll
        for (int j = 0; j < 2; ++j) {
            const int dloc = (wv & 1) * 32 + j * 16 + l15;
            const float bvv = bias2[(n0 - 1024) + dloc];
#pragma unroll
            for (int i = 0; i < 4; ++i) {
                const int tokb = (wv >> 1) * 64 + i * 16 + quad * 4;
#pragma unroll
                for (int r = 0; r < 4; ++r)
                    Ld[dloc * 136 + tokb + r] = f2bf(acc[i][j][r] + bvv);
            }
        }
        __syncthreads();
        const int dloc = t >> 2;                // 0..63
        const int tk0 = (t & 3) * 32;           // 0,32,64,96
        const int bb = m0 >> 11;
        unsigned short* dst = (unsigned short*)Cp2 +
            ((size_t)bb * 1024 + (n0 - 1024) + dloc) * LL + (m0 & (LL - 1)) + tk0;
        const unsigned short* srcp = Ld + dloc * 136 + tk0;
#pragma unroll
        for (int c = 0; c < 4; ++c)
            *(uint4*)(dst + c * 8) = *(const uint4*)(srcp + c * 8);
    }
}

// ---------------------------------------------------------------------------
// attn7: one q-tile (64 rows) per block, 8 waves = 2 k-parity groups x
// 4 waves (16 q-rows each). K/V read DIRECTLY from global (L1/L2-resident;
// per XCD: 4 combos x 512 KB = 2 MB in 4 MB L2) -- no LDS staging, no
// per-chunk vmcnt(0) drains. QK^T computed swapped (S^T = mfma(K, Q)) so
// each lane holds 4 k-adjacent P values for a single q-row (l15):
//   - Ps written as one packed b64 per sub (4 writes/chunk, was 16 b16)
//   - row-sum is a per-lane scalar; epilogue reduce = 2 shfl_xor (quads)
// One cheap convoy barrier per chunk keeps the 4-wave group in lockstep so
// L1 serves the intra-group read duplication. LDS 20KB (Ps overlaid by CB).
// Grid 1024 (32 combos x 32 tiles), longest tiles first. 8192 waves total;
// launch_bounds(512,6) -> VGPR<=84 -> 3 blocks/CU (75% occupancy).
// ---------------------------------------------------------------------------
__global__ __launch_bounds__(512, 6)
void attn7_k(const unsigned short* __restrict__ Qp,
             const unsigned short* __restrict__ Kp,
             const unsigned short* __restrict__ VpT,
             unsigned short* __restrict__ Op) {
    __shared__ unsigned short Ps[10240];       // 20 KB: [8][16][72] (18.4 KB) / CB overlay
    float* CB = (float*)Ps;                    // epilogue combine buffer (20 KB)

    const int t = threadIdx.x, lane = t & 63, wv = t >> 6;
    const int grp = wv >> 2, w4 = wv & 3;
    const int quad = lane >> 4, l15 = lane & 15;

    const int bid = blockIdx.x;
    const int xcd = bid & 7, s = bid >> 3;     // s in [0,128)
    const int combo = xcd * 4 + (s & 3);       // 4 combos per XCD (L2 locality)
    const int tile = 31 - (s >> 2);            // longest tiles dispatched first
    const int h = combo & 15, b = combo >> 4;
    const int q0 = tile * 64;
    const int rowq = q0 + w4 * 16 + l15;       // this lane's q-row (S^T column)

    // Q fragment (B operand): lane l15 = q-col, quad picks d-slice
    const unsigned short* qp = Qp + (size_t)(b * LL + rowq) * DM + h * DK;
    const bf16x8 aq0 = ld8(qp + quad * 8);
    const bf16x8 aq1 = ld8(qp + 32 + quad * 8);

    // per-lane 32-bit global offsets; uniform chunk base added per iteration
    unsigned koff[4], voff[4];
#pragma unroll
    for (int sub = 0; sub < 4; ++sub) {
        koff[sub] = (unsigned)((b * LL + sub * 16 + l15) * DM + h * DK + quad * 8);
        voff[sub] = (unsigned)(((b * NH + h) * DK + sub * 16 + l15) * LL + quad * 8);
    }

    unsigned short* PsW = Ps + wv * 1152;      // this wave's [16][72] P tile

    f32x4 acc[4] = {};
    float lsum = 0.f;

    const int nit = tile / 2 + 1;
    for (int it = 0; it < nit; ++it) {
        const int c = 2 * it + grp;
        const bool active = (c <= tile);
        __syncthreads();                       // convoy barrier (L1 locality); no LDS hazard
        if (!active) continue;
        const int kt = c * 64;
        const unsigned short* kb = Kp + (size_t)kt * DM;   // uniform -> SGPR base
        const unsigned short* vb = VpT + kt;
        const bool diag = (c == tile);

        // S^T = K_chunk @ Q^T : out col = q (l15), row = k (quad*4+r, +sub*16)
#pragma unroll
        for (int sub = 0; sub < 4; ++sub) {
            const unsigned short* kp2 = kb + koff[sub];
            const bf16x8 k0 = ld8(kp2);
            const bf16x8 k1 = ld8(kp2 + 32);
            f32x4 ss = {};
            ss = __builtin_amdgcn_mfma_f32_16x16x32_bf16(k0, aq0, ss, 0, 0, 0);
            ss = __builtin_amdgcn_mfma_f32_16x16x32_bf16(k1, aq1, ss, 0, 0, 0);
            float e[4];
            if (diag) {                        // diagonal chunk: causal mask
                const int kb4 = kt + sub * 16 + quad * 4;
#pragma unroll
                for (int r = 0; r < 4; ++r) {
                    const float x = exp2f(fmaf(ss[r], 0.18033688011112042f, -16.0f));
                    e[r] = (kb4 + r > rowq) ? 0.f : x;
                }
            } else {                           // interior: no mask
#pragma unroll
                for (int r = 0; r < 4; ++r)
                    e[r] = exp2f(fmaf(ss[r], 0.18033688011112042f, -16.0f));
            }
            lsum += (e[0] + e[1]) + (e[2] + e[3]);
            uint2 w2;
            w2.x = packt(e[0], e[1]);
            w2.y = packt(e[2], e[3]);
            *(uint2*)(PsW + l15 * 72 + sub * 16 + quad * 4) = w2;   // k-adjacent pack
        }

        // PV: A = P (lane l15 = q-row, k contiguous), B = V (VpT k-contiguous)
#pragma unroll
        for (int ks = 0; ks < 2; ++ks) {
            const bf16x8 ap = ld8(PsW + l15 * 72 + ks * 32 + quad * 8);
#pragma unroll
            for (int sub = 0; sub < 4; ++sub) {
                const bf16x8 bv = ld8(vb + voff[sub] + ks * 32);
                acc[sub] = __builtin_amdgcn_mfma_f32_16x16x32_bf16(ap, bv, acc[sub], 0, 0, 0);
            }
        }
    }

    // combine even/odd k-parity groups, normalize, write out
    __syncthreads();
    const int base = (w4 * 64 + lane) * 20;
    if (grp == 1) {
#pragma unroll
        for (int sub = 0; sub < 4; ++sub)
#pragma unroll
            for (int r = 0; r < 4; ++r) CB[base + sub * 4 + r] = acc[sub][r];
        CB[base + 16] = lsum;
    }
    __syncthreads();
    if (grp == 0) {
#pragma unroll
        for (int sub = 0; sub < 4; ++sub)
#pragma unroll
            for (int r = 0; r < 4; ++r) acc[sub][r] += CB[base + sub * 4 + r];
        lsum += CB[base + 16];
        lsum += __shfl_xor(lsum, 16, 64);      // reduce the 4 quads of this q-row
        lsum += __shfl_xor(lsum, 32, 64);
        const float inv = __builtin_amdgcn_rcpf(lsum);
        float invr[4];
#pragma unroll
        for (int r = 0; r < 4; ++r) invr[r] = __shfl(inv, quad * 4 + r, 64);
#pragma unroll
        for (int sub = 0; sub < 4; ++sub)
#pragma unroll
            for (int r = 0; r < 4; ++r)
                Op[(size_t)(b * LL + q0 + w4 * 16 + quad * 4 + r) * DM + h * DK + sub * 16 + l15] =
                    f2bf(acc[sub][r] * invr[r]);
    }
}

// ---------------------------------------------------------------------------
extern "C" void kernel_launch(void* const* d_in, const int* in_sizes, int n_in,
                              void* d_out, int out_size, void* d_ws, size_t ws_size,
                              hipStream_t stream) {
    const float* queries = (const float*)d_in[0];
    const float* keys    = (const float*)d_in[1];
    const float* Wq = (const float*)d_in[3];  const float* bq = (const float*)d_in[4];
    const float* Wd = (const float*)d_in[5];  const float* bd = (const float*)d_in[6];
    const float* Wk = (const float*)d_in[7];  const float* bk = (const float*)d_in[8];
    const float* Wv = (const float*)d_in[9];  const float* bv = (const float*)d_in[10];
    const float* Wo = (const float*)d_in[11]; const float* bo = (const float*)d_in[12];

    char* ws = (char*)d_ws;
    const size_t MB = 1048576;
    unsigned short* Qp   = (unsigned short*)(ws);
    unsigned short* Kb   = (unsigned short*)(ws + 8 * MB);
    unsigned short* Kp   = (unsigned short*)(ws + 8 * MB);
    unsigned short* Qb   = (unsigned short*)(ws + 16 * MB);
    unsigned short* VpT  = (unsigned short*)(ws + 16 * MB);
    unsigned short* WqT  = (unsigned short*)(ws + 24 * MB);
    unsigned short* Lat  = (unsigned short*)(ws + 26 * MB);
    unsigned short* WdT  = (unsigned short*)(ws + 28 * MB);
    unsigned short* WkvT = (unsigned short*)(ws + 28 * MB + 524288);
    unsigned short* Attn = (unsigned short*)(ws + 24 * MB);
    unsigned short* WoT  = (unsigned short*)(ws + 32 * MB);

    prep_k<<<4864, 256, 0, stream>>>(Wq, Wd, Wk, Wv, Wo, queries, keys,
                                     WqT, WdT, WkvT, WoT, Qb, Kb);
    gemm_k<0><<<640, 256, 0, stream>>>(Qb, WqT, bq, Qp, Kb, WdT, bd, Lat, 1024);
    gemm_k<2><<<1024, 256, 0, stream>>>(Lat, WkvT, bk, Kp, nullptr, nullptr, bv, VpT, 256);
    attn7_k<<<1024, 512, 0, stream>>>(Qp, Kp, VpT, Attn);
    gemm_k<1><<<512, 256, 0, stream>>>(Attn, WoT, bo, d_out, nullptr, nullptr, nullptr, nullptr, 1024);
}

// Round 2
// 202.225 us; speedup vs baseline: 1.4476x; 1.4476x over previous
//
#include <hip/hip_runtime.h>
#include <stdint.h>

// ---------------------------------------------------------------------------
// DS_MultiHeadLatentAttention, round 10.
// attn8 = attn6's LDS staging machinery (verified) + attn7's swapped-QK math
// (verified) + T3/T4 pipelining: K double-buffered, V issued early, counted
// vmcnt + raw s_barrier (no vmcnt(0) drain in the loop).
//   per iter: issue V(c)+K(c+2) -> vmcnt(4) [waits K(c), issued 1 iter ago]
//   -> B1 -> QK+softmax (covers V latency) -> vmcnt(2) [waits V(c)] -> B2
//   -> PV -> B3. Final K-issue clamped so vmcnt counts stay wave-uniform.
// LDS 66KB (Ks dbuf 32K + Vs 16K + Ps 18K) -> 2 blocks/CU, grid 512 exact.
// prep/gemms unchanged.
// Dispatches: prep, gemmQLat(640), gemmKV(1024), attn(512), gemmO(512).
// Workspace (34 MB, time-phased):
//   [0,8M)   Qp      [8,16M)  Kb -> Kp      [16,24M) Qb -> VpT
//   [24,32M) WqT(2M)|Lat(2M)|WdT(.5M)|WkvT(1M) -> Attn
//   [32,34M) WoT
// ---------------------------------------------------------------------------

#define DM 1024
#define NH 16
#define DK 64
#define LL 2048

typedef float  f32x4  __attribute__((ext_vector_type(4)));
typedef __bf16 bf16x8 __attribute__((ext_vector_type(8)));
typedef short  s16x8  __attribute__((ext_vector_type(8)));

__device__ __forceinline__ unsigned short f2bf(float f) {
    union { float f; unsigned int u; } v; v.f = f;
    return (unsigned short)((v.u + 0x7fffu + ((v.u >> 16) & 1u)) >> 16);
}
__device__ __forceinline__ unsigned int pack2(float a, float b) {
    return (unsigned int)f2bf(a) | ((unsigned int)f2bf(b) << 16);
}
// truncating pack (exp values only)
__device__ __forceinline__ unsigned int packt(float a, float b) {
    union { float f; unsigned int u; } x, y; x.f = a; y.f = b;
    return (x.u >> 16) | (y.u & 0xffff0000u);
}
__device__ __forceinline__ bf16x8 ld8(const unsigned short* p) {
    s16x8 s = *(const s16x8*)p;
    return __builtin_bit_cast(bf16x8, s);
}
__device__ __forceinline__ void gl16(const void* g, void* l) {
    __builtin_amdgcn_global_load_lds((__attribute__((address_space(1))) void*)(g),
                                     (__attribute__((address_space(3))) void*)(l),
                                     16, 0, 0);
}

// ---------------------------------------------------------------------------
// prep: 5 weight transposes (fp32 [K][N] -> bf16 [N][K]) + queries/keys
// fp32 -> bf16. Grid = 4864.
// ---------------------------------------------------------------------------
__global__ __launch_bounds__(256)
void prep_k(const float* __restrict__ Wq, const float* __restrict__ Wd,
            const float* __restrict__ Wk, const float* __restrict__ Wv,
            const float* __restrict__ Wo, const float* __restrict__ queries,
            const float* __restrict__ keys,
            unsigned short* __restrict__ WqT, unsigned short* __restrict__ WdT,
            unsigned short* __restrict__ WkvT, unsigned short* __restrict__ WoT,
            unsigned short* __restrict__ Qb, unsigned short* __restrict__ Kb) {
    int bid = blockIdx.x;
    const int t = threadIdx.x;

    const float* W; unsigned short* WT; int TK, TN;
    if (bid < 1024)      { W = Wq; WT = WqT;  TK = 1024; TN = 1024; }
    else if (bid < 1280) { bid -= 1024; W = Wd; WT = WdT; TK = 1024; TN = 256; }
    else if (bid < 1536) { bid -= 1280; W = Wk; WT = WkvT; TK = 256; TN = 1024; }
    else if (bid < 1792) { bid -= 1536; W = Wv; WT = WkvT + (size_t)1024 * 256; TK = 256; TN = 1024; }
    else if (bid < 2816) { bid -= 1792; W = Wo; WT = WoT;  TK = 1024; TN = 1024; }
    else {
        bid -= 2816;
        const float* src; unsigned short* dst;
        if (bid < 1024) { src = queries; dst = Qb; }
        else            { bid -= 1024; src = keys; dst = Kb; }
        const size_t base = (size_t)bid * 4096;
#pragma unroll
        for (int i = 0; i < 4; ++i) {
            float4 f = *(const float4*)(src + base + (size_t)(i * 256 + t) * 4);
            uint2 u = { pack2(f.x, f.y), pack2(f.z, f.w) };
            *(uint2*)(dst + base + (size_t)(i * 256 + t) * 4) = u;
        }
        return;
    }
    __shared__ float tile[32][33];
    const int tx = t & 31, ty = t >> 5;
    const int bx = bid % (TK / 32), by = bid / (TK / 32);
    const int k0 = bx * 32, n0 = by * 32;
#pragma unroll
    for (int i = 0; i < 4; ++i)
        tile[ty + 8 * i][tx] = W[(size_t)(k0 + ty + 8 * i) * TN + n0 + tx];
    __syncthreads();
#pragma unroll
    for (int i = 0; i < 4; ++i)
        WT[(size_t)(n0 + ty + 8 * i) * TK + k0 + tx] = f2bf(tile[tx][ty + 8 * i]);
}

// ---------------------------------------------------------------------------
// GEMM staging + compute helpers (128x64 tile, BK=64).
// ---------------------------------------------------------------------------
__device__ __forceinline__ void stage6(const unsigned short* gA, const unsigned short* gB,
                                       int kk, int K,
                                       unsigned short* lA, unsigned short* lB) {
#pragma unroll
    for (int s = 0; s < 4; ++s) gl16(gA + kk + (size_t)s * 8 * K, lA + s * 512);
#pragma unroll
    for (int s = 0; s < 2; ++s) gl16(gB + kk + (size_t)s * 8 * K, lB + s * 512);
}

__device__ __forceinline__ void mfma16(const unsigned short* As, const unsigned short* Bs,
                                       const int aoff[4][2], const int boff[2][2],
                                       f32x4 acc[4][2]) {
#pragma unroll
    for (int ks = 0; ks < 2; ++ks) {
        bf16x8 a[4], b[2];
#pragma unroll
        for (int i = 0; i < 4; ++i) a[i] = ld8(As + aoff[i][ks]);
#pragma unroll
        for (int j = 0; j < 2; ++j) b[j] = ld8(Bs + boff[j][ks]);
#pragma unroll
        for (int i = 0; i < 4; ++i)
#pragma unroll
            for (int j = 0; j < 2; ++j)
                acc[i][j] = __builtin_amdgcn_mfma_f32_16x16x32_bf16(a[i], b[j], acc[i][j], 0, 0, 0);
    }
}

// ---------------------------------------------------------------------------
// GEMM 128(M) x 64(N) tile, BK=64, 4 waves 2x2 (wave = 64m x 32n, 4x2 accs).
// LDS double-buffer (Sh0/Sh1, compile-time selection), one barrier per iter.
// XCD-clustered: xcd = bid&7 sweeps all n over a small m-window.
// MODE 0: fused Q+Lat (K=1024). bid<512: Qb@WqT+bq -> Qp bf16 [row*1024].
//         bid>=512 (128 blocks): Kb@WdT+bd -> Lat bf16 [row*256].
// MODE 1: Attn@WoT+bo -> f32 [row*1024]. grid 512, K=1024.
// MODE 2: fused K|V (K=256, N=2048): col<1024 -> Kp bf16 [row*1024];
//         col>=1024 -> VpT [b][col-1024][l] via LDS-transposed epilogue.
// ---------------------------------------------------------------------------
template<int MODE>
__global__ __launch_bounds__(256)
void gemm_k(const unsigned short* __restrict__ Ap, const unsigned short* __restrict__ Bt,
            const float* __restrict__ bias, void* __restrict__ Cp,
            const unsigned short* __restrict__ Ap2, const unsigned short* __restrict__ Bt2,
            const float* __restrict__ bias2, void* __restrict__ Cp2,
            int K) {
    __shared__ unsigned short Sh0[12288];     // As0 8192 + Bs0 4096 shorts (24 KB)
    __shared__ unsigned short Sh1[12288];     // As1 + Bs1 (24 KB)

    int bid = blockIdx.x;
    const unsigned short* A;
    const unsigned short* B;
    const float* bs;
    bool second = false;
    int m0, n0;
    if (MODE == 0 && bid >= 512) {            // Lat part: 128 blocks, N=256
        bid -= 512; A = Ap2; B = Bt2; bs = bias2; second = true;
        const int xcd = bid & 7, s = bid >> 3;            // s in [0,16)
        n0 = (s & 3) * 64; m0 = (xcd * 4 + (s >> 2)) * 128;
    } else {
        A = Ap; B = Bt; bs = bias;
        const int xcd = bid & 7, s = bid >> 3;
        if (MODE == 2) { n0 = (s & 31) * 64; m0 = (xcd * 4 + (s >> 5)) * 128; }
        else           { n0 = (s & 15) * 64; m0 = (xcd * 4 + (s >> 4)) * 128; }
    }

    const int t = threadIdx.x, lane = t & 63, wv = t >> 6;
    const int quad = lane >> 4, l15 = lane & 15;

    const int lr8 = lane >> 3;                 // 0..7
    const int g8 = (lane & 7) ^ (lr8 & 7);     // swizzled k-chunk
    const unsigned short* gA = A + (size_t)(m0 + wv * 32 + lr8) * K + g8 * 8;
    const unsigned short* gB = B + (size_t)(n0 + wv * 16 + lr8) * K + g8 * 8;
    unsigned short* lA0 = Sh0 + wv * 2048;
    unsigned short* lB0 = Sh0 + 8192 + wv * 1024;
    unsigned short* lA1 = Sh1 + wv * 2048;
    unsigned short* lB1 = Sh1 + 8192 + wv * 1024;

    int aoff[4][2], boff[2][2];
#pragma unroll
    for (int i = 0; i < 4; ++i) {
        const int ra = (wv >> 1) * 64 + i * 16 + l15;
#pragma unroll
        for (int ks = 0; ks < 2; ++ks)
            aoff[i][ks] = ra * 64 + (((ks * 4 + quad) ^ (ra & 7)) << 3);
    }
#pragma unroll
    for (int j = 0; j < 2; ++j) {
        const int rb = (wv & 1) * 32 + j * 16 + l15;
#pragma unroll
        for (int ks = 0; ks < 2; ++ks)
            boff[j][ks] = rb * 64 + (((ks * 4 + quad) ^ (rb & 7)) << 3);
    }

    f32x4 acc[4][2] = {};
    const int niter = K >> 6;                  // 16 or 4 (always even)

    stage6(gA, gB, 0, K, lA0, lB0);
    __syncthreads();                           // tile 0 resident in Sh0
    for (int it = 0; it < niter; it += 2) {
        const int kk = it << 6;
        // even iter: prefetch -> Sh1, compute Sh0
        if (it + 1 < niter) stage6(gA, gB, kk + 64, K, lA1, lB1);
        mfma16(Sh0, Sh0 + 8192, aoff, boff, acc);
        __syncthreads();                       // drains Sh1 gl16s (overlapped)
        if (it + 1 < niter) {
            // odd iter: prefetch -> Sh0, compute Sh1
            if (it + 2 < niter) stage6(gA, gB, kk + 128, K, lA0, lB0);
            mfma16(Sh1, Sh1 + 8192, aoff, boff, acc);
            __syncthreads();
        }
    }

    const bool isV = (MODE == 2) && (n0 >= 1024);
    if (!isV) {
#pragma unroll
        for (int j = 0; j < 2; ++j) {
            const int col = n0 + (wv & 1) * 32 + j * 16 + l15;
            const float bvv = bs[col];
#pragma unroll
            for (int i = 0; i < 4; ++i) {
                const int rowb = m0 + (wv >> 1) * 64 + i * 16 + quad * 4;
#pragma unroll
                for (int r = 0; r < 4; ++r) {
                    const float v = acc[i][j][r] + bvv;
                    const int row = rowb + r;
                    if (MODE == 1)
                        ((float*)Cp)[(size_t)row * 1024 + col] = v;
                    else if (second)
                        ((unsigned short*)Cp2)[(size_t)row * 256 + col] = f2bf(v);
                    else
                        ((unsigned short*)Cp)[(size_t)row * 1024 + col] = f2bf(v);
                }
            }
        }
    } else {
        // V part: transpose 128tok x 64d tile through LDS, store coalesced
        // to VpT[(b*1024 + d)*2048 + l].  Ld layout: [d][tok], stride 136.
        unsigned short* Ld = Sh0;               // 64*136 shorts = 17408 B
#pragma unroll
        for (int j = 0; j < 2; ++j) {
            const int dloc = (wv & 1) * 32 + j * 16 + l15;
            const float bvv = bias2[(n0 - 1024) + dloc];
#pragma unroll
            for (int i = 0; i < 4; ++i) {
                const int tokb = (wv >> 1) * 64 + i * 16 + quad * 4;
#pragma unroll
                for (int r = 0; r < 4; ++r)
                    Ld[dloc * 136 + tokb + r] = f2bf(acc[i][j][r] + bvv);
            }
        }
        __syncthreads();
        const int dloc = t >> 2;                // 0..63
        const int tk0 = (t & 3) * 32;           // 0,32,64,96
        const int bb = m0 >> 11;
        unsigned short* dst = (unsigned short*)Cp2 +
            ((size_t)bb * 1024 + (n0 - 1024) + dloc) * LL + (m0 & (LL - 1)) + tk0;
        const unsigned short* srcp = Ld + dloc * 136 + tk0;
#pragma unroll
        for (int c = 0; c < 4; ++c)
            *(uint4*)(dst + c * 8) = *(const uint4*)(srcp + c * 8);
    }
}

// ---------------------------------------------------------------------------
// attn8: grid 512, paired q-tiles (j, 31-j), 2 k-parity groups x 4 waves.
// LDS-staged K/V (swizzled gl16, attn6 machinery) + swapped QK^T softmax
// (attn7 math). Pipelined: K double-buffered across iterations, V issued at
// iter top and consumed after QK+softmax. Raw s_barrier + counted vmcnt --
// the stage latency that attn6 serially exposed (vmcnt(0) drain per chunk)
// is now covered by compute. Final K-issue clamped to keep counts uniform.
// LDS: Ks[2][2][4096] 32K + Vs[2][4096] 16K + Ps 18K = 66K -> 2 blocks/CU.
// Epilogue CB overlays Ks (protected by full __syncthreads drains).
// ---------------------------------------------------------------------------
__global__ __launch_bounds__(512, 4)
void attn8_k(const unsigned short* __restrict__ Qp,
             const unsigned short* __restrict__ Kp,
             const unsigned short* __restrict__ VpT,
             unsigned short* __restrict__ Op) {
    __shared__ unsigned short Ks[2][2][4096];  // [grp][buf][64k x 64d]
    __shared__ unsigned short Vs[2][4096];     // [grp][64d x 64k]
    __shared__ unsigned short Ps[8][1152];     // per-wave [16q][72k]
    float* CB = (float*)&Ks[0][0][0];          // epilogue combine (20KB < 32KB)

    const int t = threadIdx.x, lane = t & 63, wv = t >> 6;
    const int grp = wv >> 2, w4 = wv & 3;
    const int quad = lane >> 4, l15 = lane & 15;

    const int bid = blockIdx.x;
    const int xcd = bid & 7, s = bid >> 3;
    const int pair = s & 15;
    const int combo = xcd * 4 + (s >> 4);      // 4 combos per XCD (L2 locality)
    const int h = combo & 15, b = combo >> 4;

    const int srow = w4 * 16 + (lane >> 3);
    const int g8 = (lane & 7) ^ ((lane >> 3) & 7);
    const int sw = l15 & 7;
    unsigned short* PsW = Ps[wv];

    const unsigned short* Kbase = Kp + (size_t)(b * LL + srow) * DM + h * DK + g8 * 8;
    const unsigned short* Vbase = VpT + ((size_t)(b * NH + h) * DK + srow) * LL + g8 * 8;
    unsigned short* lV = &Vs[grp][w4 * 1024];

    for (int tsel = 0; tsel < 2; ++tsel) {
        const int tile = tsel ? (31 - pair) : pair;
        const int q0 = tile * 64;
        const int rowq = q0 + w4 * 16 + l15;   // this lane's q-row

        if (tsel) __syncthreads();             // CB reads done before restage

        const unsigned short* qp = Qp + (size_t)(b * LL + rowq) * DM + h * DK;
        const bf16x8 aq0 = ld8(qp + quad * 8);
        const bf16x8 aq1 = ld8(qp + 32 + quad * 8);

        f32x4 acc[4] = {};
        float lsum = 0.f;

        // prologue: stage K(grp) -> Ks[grp][0]
        if (grp <= tile) {
            const unsigned short* kg = Kbase + (size_t)(grp * 64) * DM;
            unsigned short* lK = &Ks[grp][0][w4 * 1024];
            gl16(kg, lK); gl16(kg + (size_t)8 * DM, lK + 512);
        }

        const int nit = tile / 2 + 1;
        for (int it = 0; it < nit; ++it) {
            const int c = 2 * it + grp;        // wave-uniform
            const int cur = it & 1;
            const bool active = (c <= tile);
            const int kt = c * 64;

            if (active) {
                // issue V(c) -> Vs[grp] (consumed after B2 this iter)
                const unsigned short* vg = Vbase + kt;
                gl16(vg, lV); gl16(vg + (size_t)8 * LL, lV + 512);
                // issue K(c+2) -> Ks[grp][cur^1] (clamped: uniform vmcnt)
                const int c2 = (c + 2 <= tile) ? (c + 2) : tile;
                const unsigned short* kg = Kbase + (size_t)(c2 * 64) * DM;
                unsigned short* lK = &Ks[grp][cur ^ 1][w4 * 1024];
                gl16(kg, lK); gl16(kg + (size_t)8 * DM, lK + 512);
            }
            asm volatile("s_waitcnt vmcnt(4)" ::: "memory");  // K(c) landed
            __builtin_amdgcn_s_barrier();                     // B1
            __builtin_amdgcn_sched_barrier(0);

            if (active) {
                const unsigned short* Kc = Ks[grp][cur];
                const bool diag = (c == tile);
#pragma unroll
                for (int sub = 0; sub < 4; ++sub) {
                    const int base2 = (sub * 16 + l15) * 64;
                    const bf16x8 k0 = ld8(Kc + base2 + ((quad ^ sw) << 3));
                    const bf16x8 k1 = ld8(Kc + base2 + (((4 + quad) ^ sw) << 3));
                    f32x4 ss = {};
                    ss = __builtin_amdgcn_mfma_f32_16x16x32_bf16(k0, aq0, ss, 0, 0, 0);
                    ss = __builtin_amdgcn_mfma_f32_16x16x32_bf16(k1, aq1, ss, 0, 0, 0);
                    float e[4];
                    if (diag) {                // diagonal chunk: causal mask
                        const int kb4 = kt + sub * 16 + quad * 4;
#pragma unroll
                        for (int r = 0; r < 4; ++r) {
                            const float x = exp2f(fmaf(ss[r], 0.18033688011112042f, -16.0f));
                            e[r] = (kb4 + r > rowq) ? 0.f : x;
                        }
                    } else {                   // interior: no mask
#pragma unroll
                        for (int r = 0; r < 4; ++r)
                            e[r] = exp2f(fmaf(ss[r], 0.18033688011112042f, -16.0f));
                    }
                    lsum += (e[0] + e[1]) + (e[2] + e[3]);
                    uint2 w2;
                    w2.x = packt(e[0], e[1]);
                    w2.y = packt(e[2], e[3]);
                    *(uint2*)(PsW + l15 * 72 + sub * 16 + quad * 4) = w2;
                }
            }
            asm volatile("s_waitcnt vmcnt(2)" ::: "memory");  // V(c) landed
            __builtin_amdgcn_s_barrier();                     // B2
            __builtin_amdgcn_sched_barrier(0);

            if (active) {
#pragma unroll
                for (int ks = 0; ks < 2; ++ks) {
                    const bf16x8 ap = ld8(PsW + l15 * 72 + ks * 32 + quad * 8);
#pragma unroll
                    for (int sub = 0; sub < 4; ++sub) {
                        const bf16x8 bv = ld8(&Vs[grp][(sub * 16 + l15) * 64 +
                                                       (((ks * 4 + quad) ^ sw) << 3)]);
                        acc[sub] = __builtin_amdgcn_mfma_f32_16x16x32_bf16(ap, bv, acc[sub], 0, 0, 0);
                    }
                }
            }
            __builtin_amdgcn_s_barrier();                     // B3: Vs free
            __builtin_amdgcn_sched_barrier(0);
        }

        // combine even/odd k-parity groups, normalize, write out.
        __syncthreads();                       // full drain (incl. leftover K)
        const int base = (w4 * 64 + lane) * 20;
        if (grp == 1) {
#pragma unroll
            for (int sub = 0; sub < 4; ++sub)
#pragma unroll
                for (int r = 0; r < 4; ++r) CB[base + sub * 4 + r] = acc[sub][r];
            CB[base + 16] = lsum;
        }
        __syncthreads();
        if (grp == 0) {
#pragma unroll
            for (int sub = 0; sub < 4; ++sub)
#pragma unroll
                for (int r = 0; r < 4; ++r) acc[sub][r] += CB[base + sub * 4 + r];
            lsum += CB[base + 16];
            lsum += __shfl_xor(lsum, 16, 64);  // reduce quads of this q-row
            lsum += __shfl_xor(lsum, 32, 64);
            const float inv = __builtin_amdgcn_rcpf(lsum);
            float invr[4];
#pragma unroll
            for (int r = 0; r < 4; ++r) invr[r] = __shfl(inv, quad * 4 + r, 64);
#pragma unroll
            for (int sub = 0; sub < 4; ++sub)
#pragma unroll
                for (int r = 0; r < 4; ++r)
                    Op[(size_t)(b * LL + q0 + w4 * 16 + quad * 4 + r) * DM + h * DK + sub * 16 + l15] =
                        f2bf(acc[sub][r] * invr[r]);
        }
    }
}

// ---------------------------------------------------------------------------
extern "C" void kernel_launch(void* const* d_in, const int* in_sizes, int n_in,
                              void* d_out, int out_size, void* d_ws, size_t ws_size,
                              hipStream_t stream) {
    const float* queries = (const float*)d_in[0];
    const float* keys    = (const float*)d_in[1];
    const float* Wq = (const float*)d_in[3];  const float* bq = (const float*)d_in[4];
    const float* Wd = (const float*)d_in[5];  const float* bd = (const float*)d_in[6];
    const float* Wk = (const float*)d_in[7];  const float* bk = (const float*)d_in[8];
    const float* Wv = (const float*)d_in[9];  const float* bv = (const float*)d_in[10];
    const float* Wo = (const float*)d_in[11]; const float* bo = (const float*)d_in[12];

    char* ws = (char*)d_ws;
    const size_t MB = 1048576;
    unsigned short* Qp   = (unsigned short*)(ws);
    unsigned short* Kb   = (unsigned short*)(ws + 8 * MB);
    unsigned short* Kp   = (unsigned short*)(ws + 8 * MB);
    unsigned short* Qb   = (unsigned short*)(ws + 16 * MB);
    unsigned short* VpT  = (unsigned short*)(ws + 16 * MB);
    unsigned short* WqT  = (unsigned short*)(ws + 24 * MB);
    unsigned short* Lat  = (unsigned short*)(ws + 26 * MB);
    unsigned short* WdT  = (unsigned short*)(ws + 28 * MB);
    unsigned short* WkvT = (unsigned short*)(ws + 28 * MB + 524288);
    unsigned short* Attn = (unsigned short*)(ws + 24 * MB);
    unsigned short* WoT  = (unsigned short*)(ws + 32 * MB);

    prep_k<<<4864, 256, 0, stream>>>(Wq, Wd, Wk, Wv, Wo, queries, keys,
                                     WqT, WdT, WkvT, WoT, Qb, Kb);
    gemm_k<0><<<640, 256, 0, stream>>>(Qb, WqT, bq, Qp, Kb, WdT, bd, Lat, 1024);
    gemm_k<2><<<1024, 256, 0, stream>>>(Lat, WkvT, bk, Kp, nullptr, nullptr, bv, VpT, 256);
    attn8_k<<<512, 512, 0, stream>>>(Qp, Kp, VpT, Attn);
    gemm_k<1><<<512, 256, 0, stream>>>(Attn, WoT, bo, d_out, nullptr, nullptr, nullptr, nullptr, 1024);
}